// Round 1
// baseline (169.426 us; speedup 1.0000x reference)
//
#include <hip/hip_runtime.h>

// FFF tree-traversal kernel for MI355X.
// BATCH=32768 rows, N_IN=N_OUT=1024, DEPTH=10 (11 levels), N_NODES=2047.
// One 64-lane wave per batch row. Lane i owns elements c*256 + i*4 + {0..3},
// c=0..3, so every global access is a coalesced float4 (1 KiB / wave / instr).

#define FFF_BATCH 32768
#define FFF_NIN   1024
#define FFF_NOUT  1024
#define FFF_LEVELS 11

__global__ __launch_bounds__(256, 4) void FFF_86122684220310_kernel(
    const float* __restrict__ x,
    const float* __restrict__ w1s,
    const float* __restrict__ w2s,
    float* __restrict__ y)
{
    const int wavesPerBlock = blockDim.x >> 6;
    const int row  = blockIdx.x * wavesPerBlock + (threadIdx.x >> 6);
    const int lane = threadIdx.x & 63;
    if (row >= FFF_BATCH) return;

    // ---- load x row into registers (16 floats/lane, coalesced float4) ----
    const float4* x4 = reinterpret_cast<const float4*>(x + (size_t)row * FFF_NIN);
    float4 xv[4];
#pragma unroll
    for (int c = 0; c < 4; ++c) xv[c] = x4[c * 64 + lane];

    float4 acc[4];
#pragma unroll
    for (int c = 0; c < 4; ++c) acc[c] = make_float4(0.f, 0.f, 0.f, 0.f);

    int node = 0;
#pragma unroll
    for (int l = 0; l < FFF_LEVELS; ++l) {
        // ---- dot(x, w1s[node]) ----
        const float4* w14 = reinterpret_cast<const float4*>(w1s + (size_t)node * FFF_NIN);
        float4 wv0 = w14[0 * 64 + lane];
        float4 wv1 = w14[1 * 64 + lane];
        float4 wv2 = w14[2 * 64 + lane];
        float4 wv3 = w14[3 * 64 + lane];

        // issue w2 load early: it doesn't gate the traversal-critical path
        const float4* w24 = reinterpret_cast<const float4*>(w2s + (size_t)node * FFF_NOUT);
        float4 uv0 = w24[0 * 64 + lane];
        float4 uv1 = w24[1 * 64 + lane];
        float4 uv2 = w24[2 * 64 + lane];
        float4 uv3 = w24[3 * 64 + lane];

        float p = 0.f;
        p = fmaf(xv[0].x, wv0.x, p); p = fmaf(xv[0].y, wv0.y, p);
        p = fmaf(xv[0].z, wv0.z, p); p = fmaf(xv[0].w, wv0.w, p);
        p = fmaf(xv[1].x, wv1.x, p); p = fmaf(xv[1].y, wv1.y, p);
        p = fmaf(xv[1].z, wv1.z, p); p = fmaf(xv[1].w, wv1.w, p);
        p = fmaf(xv[2].x, wv2.x, p); p = fmaf(xv[2].y, wv2.y, p);
        p = fmaf(xv[2].z, wv2.z, p); p = fmaf(xv[2].w, wv2.w, p);
        p = fmaf(xv[3].x, wv3.x, p); p = fmaf(xv[3].y, wv3.y, p);
        p = fmaf(xv[3].z, wv3.z, p); p = fmaf(xv[3].w, wv3.w, p);

        // 64-lane butterfly reduce; every lane ends with the full sum
#pragma unroll
        for (int m = 1; m < 64; m <<= 1)
            p += __shfl_xor(p, m, 64);
        const float score = p;

        // ---- y += score * w2s[node] ----
        acc[0].x = fmaf(score, uv0.x, acc[0].x); acc[0].y = fmaf(score, uv0.y, acc[0].y);
        acc[0].z = fmaf(score, uv0.z, acc[0].z); acc[0].w = fmaf(score, uv0.w, acc[0].w);
        acc[1].x = fmaf(score, uv1.x, acc[1].x); acc[1].y = fmaf(score, uv1.y, acc[1].y);
        acc[1].z = fmaf(score, uv1.z, acc[1].z); acc[1].w = fmaf(score, uv1.w, acc[1].w);
        acc[2].x = fmaf(score, uv2.x, acc[2].x); acc[2].y = fmaf(score, uv2.y, acc[2].y);
        acc[2].z = fmaf(score, uv2.z, acc[2].z); acc[2].w = fmaf(score, uv2.w, acc[2].w);
        acc[3].x = fmaf(score, uv3.x, acc[3].x); acc[3].y = fmaf(score, uv3.y, acc[3].y);
        acc[3].z = fmaf(score, uv3.z, acc[3].z); acc[3].w = fmaf(score, uv3.w, acc[3].w);

        node = node * 2 + 1 + ((score > 0.f) ? 1 : 0);
    }

    float4* y4 = reinterpret_cast<float4*>(y + (size_t)row * FFF_NOUT);
#pragma unroll
    for (int c = 0; c < 4; ++c) y4[c * 64 + lane] = acc[c];
}

extern "C" void kernel_launch(void* const* d_in, const int* in_sizes, int n_in,
                              void* d_out, int out_size, void* d_ws, size_t ws_size,
                              hipStream_t stream) {
    const float* x   = (const float*)d_in[0];
    const float* w1s = (const float*)d_in[1];
    const float* w2s = (const float*)d_in[2];
    // d_in[3] = depth scalar (hardcoded to 10)
    float* y = (float*)d_out;

    const int threads = 256;              // 4 waves -> 4 rows per block
    const int blocks  = FFF_BATCH / 4;    // 8192
    FFF_86122684220310_kernel<<<blocks, threads, 0, stream>>>(x, w1s, w2s, y);
}